// Round 14
// baseline (738.817 us; speedup 1.0000x reference)
//
#include <hip/hip_runtime.h>

// EquivariantConvLayer — Round 14.
// r13 byte-identical except pass-size selection: prefer npp=5000 so the
// 102MB GH producer->consumer buffer stays Infinity-Cache(256MB)-resident
// across the gGH->msg01 handoff (at npp=10000 GH=205MB was evicted by the
// concurrent es/msg streams: msg01 FETCH=188MB ~= GH size -> HBM-served).
// GH is 820MB of the pipeline's ~1.5GB traffic; L3-serving it is the last
// structural lever at this design point.

#define NN 20000
#define EE 640000
#define EPMAX 940032

typedef _Float16 half8 __attribute__((ext_vector_type(8)));
typedef float f32x4 __attribute__((ext_vector_type(4)));

__device__ __forceinline__ float silu_f(float x) { return x / (1.0f + __expf(-x)); }
__device__ __forceinline__ _Float16 u2h(unsigned short u) {
    union { unsigned short u; _Float16 h; } c; c.u = u; return c.h;
}
__device__ __forceinline__ unsigned short h2u(_Float16 h) {
    union { unsigned short u; _Float16 h; } c; c.h = h; return c.u;
}
__device__ __forceinline__ half8 pack8(float4 a, float4 b) {
    half8 h;
    h[0]=(_Float16)a.x; h[1]=(_Float16)a.y; h[2]=(_Float16)a.z; h[3]=(_Float16)a.w;
    h[4]=(_Float16)b.x; h[5]=(_Float16)b.y; h[6]=(_Float16)b.z; h[7]=(_Float16)b.w;
    return h;
}

// ---- workspace layout (bytes) ----
#define OFF_HIST  0ull
#define OFF_RS    81920ull
#define OFF_CUR   163840ull
#define OFF_FLAG  245760ull
#define F_OUTD    262144ull
#define F_PSP     360448ull
#define F_CURS    458752ull
#define F_AUX     557056ull       // NN*512 f16: g[32], CXW[96]@32, VW[192]@128
#define F_DSTP    21037056ull
#define F_PDP     24797184ull
#define F_WMLP    28557312ull
#define F_WSV     28581888ull
#define F_WX2     28585984ull
#define F_WVV     28588032ull
#define F_WSSG    28592128ull
#define F_WVS3    29116416ull
#define F_ES      29247488ull     // EPMAX*128B
#define F_MSG     149571584ull    // EE*320B
#define F_GH      354371584ull    // npp*20480B
#define NEED_F(npp) (F_GH + (unsigned long long)(npp) * 20480ull)

// ---------------------------------------------------------------------------
__global__ void detect_idx_kernel(const int* __restrict__ eidx, int* __restrict__ flag) {
    int odd_nz = 0, even_nz = 0;
    for (int k = 0; k < 64; ++k) {
        if (eidx[2 * k + 1] != 0) odd_nz = 1;
        if (eidx[2 * k] != 0) even_nz = 1;
    }
    *flag = (!odd_nz && even_nz) ? 1 : 0;
}

__device__ __forceinline__ void load_sd(const int* eidx, const int* flag, int e,
                                        int& s_, int& d_) {
    if (*flag) { s_ = (int)((const long long*)eidx)[e]; d_ = (int)((const long long*)eidx)[EE + e]; }
    else       { s_ = eidx[e];                          d_ = eidx[EE + e]; }
}

__global__ __launch_bounds__(256) void hist2_kernel(
    const int* __restrict__ eidx, const int* __restrict__ flag,
    int* __restrict__ hist, int* __restrict__ outd)
{
    const int e = blockIdx.x * 256 + threadIdx.x;
    int s_, d_; load_sd(eidx, flag, e, s_, d_);
    atomicAdd(hist + d_, 1);
    atomicAdd(outd + s_, 1);
}

__global__ __launch_bounds__(1024) void scan2_kernel(
    const int* __restrict__ hist, const int* __restrict__ outd,
    int* __restrict__ rs, int* __restrict__ cur,
    int* __restrict__ psP, int* __restrict__ curS)
{
    __shared__ int part[1024];
    const int t = threadIdx.x;
    const int base = t * 20;
    {
        int loc[20]; int tot = 0;
#pragma unroll
        for (int k = 0; k < 20; ++k) {
            int n = base + k;
            int h = (n < NN) ? hist[n] : 0;
            loc[k] = tot; tot += h;
        }
        part[t] = tot;
        __syncthreads();
        for (int off = 1; off < 1024; off <<= 1) {
            int v = (t >= off) ? part[t - off] : 0;
            __syncthreads();
            part[t] += v;
            __syncthreads();
        }
        int excl = part[t] - tot;
#pragma unroll
        for (int k = 0; k < 20; ++k) {
            int n = base + k;
            if (n < NN) { rs[n] = excl + loc[k]; cur[n] = excl + loc[k]; }
        }
        if (t == 1023) rs[NN] = part[1023];
    }
    __syncthreads();
    {
        int loc[20]; int tot = 0;
#pragma unroll
        for (int k = 0; k < 20; ++k) {
            int n = base + k;
            int p = (n < NN) ? ((outd[n] + 15) & ~15) : 0;
            loc[k] = tot; tot += p;
        }
        part[t] = tot;
        __syncthreads();
        for (int off = 1; off < 1024; off <<= 1) {
            int v = (t >= off) ? part[t - off] : 0;
            __syncthreads();
            part[t] += v;
            __syncthreads();
        }
        int excl = part[t] - tot;
#pragma unroll
        for (int k = 0; k < 20; ++k) {
            int n = base + k;
            if (n < NN) { psP[n] = excl + loc[k]; curS[n] = excl + loc[k]; }
        }
    }
}

// ---------------------------------------------------------------------------
__global__ __launch_bounds__(256) void prep2_kernel(
    const float* __restrict__ wss, const float* __restrict__ wvv,
    const float* __restrict__ wsv, const float* __restrict__ wvs,
    const float* __restrict__ wx,
    const float* __restrict__ W1, const float* __restrict__ W2,
    const float* __restrict__ W3, char* __restrict__ ws)
{
    int id = blockIdx.x * 256 + threadIdx.x;
    if (id >= 43136) return;
    int l = id & 63;
    int l4 = l >> 4, l16 = l & 15;
    half8 o;
    _Float16* dst;
    if (id < 32768) {                        // WSSG
        int i = id;
        int f = i >> 6;
        int q = f >> 3, kfp = (f >> 2) & 1, nfp = f & 3;
#pragma unroll
        for (int j = 0; j < 8; j++) {
            int p = kfp * 32 + l4 * 8 + j;
            int cc = q * 64 + nfp * 16 + l16;
            int jc = cc & 7, lc = (cc >> 3) & 63, fi = cc >> 9;
            int kfc = fi >> 2, nfc = fi & 3;
            int h = kfc * 32 + (lc >> 4) * 8 + jc;
            int oo = nfc * 16 + (lc & 15);
            o[j] = (_Float16)wss[((size_t)p * 64 + h) * 64 + oo];
        }
        dst = (_Float16*)(ws + F_WSSG) + (size_t)i * 8;
    } else if (id < 40960) {                 // WVS3
        int i = id - 32768;
        int f = i >> 6;
        int col = f * 16 + l16;
#pragma unroll
        for (int j = 0; j < 8; j++) {
            int d = l4 * 8 + j;
            o[j] = (_Float16)wvs[((size_t)d * 64 + (col & 63)) * 32 + (col >> 6)];
        }
        dst = (_Float16*)(ws + F_WVS3) + (size_t)i * 8;
    } else if (id < 42496) {                 // WMLP
        int i = id - 40960; int f = i >> 6;
        int layer = f >> 3, kf = (f >> 2) & 1, nf = f & 3;
        const float* W = layer == 0 ? W1 : (layer == 1 ? W2 : W3);
#pragma unroll
        for (int j = 0; j < 8; j++)
            o[j] = (_Float16)W[(kf * 32 + l4 * 8 + j) * 64 + nf * 16 + l16];
        dst = (_Float16*)(ws + F_WMLP) + (size_t)i * 8;
    } else if (id < 42752) {                 // WVV
        int i = id - 42496; int nf = i >> 6;
#pragma unroll
        for (int j = 0; j < 8; j++)
            o[j] = (_Float16)wvv[(l4 * 8 + j) * 64 + nf * 16 + l16];
        dst = (_Float16*)(ws + F_WVV) + (size_t)i * 8;
    } else if (id < 43008) {                 // WSV
        int i = id - 42752; int frag = i >> 6;
        int kf = frag >> 1, nf = frag & 1;
#pragma unroll
        for (int j = 0; j < 8; j++)
            o[j] = (_Float16)wsv[(kf * 32 + l4 * 8 + j) * 32 + nf * 16 + l16];
        dst = (_Float16*)(ws + F_WSV) + (size_t)i * 8;
    } else {                                 // WX2
        int i = id - 43008; int nf = i >> 6;
#pragma unroll
        for (int j = 0; j < 8; j++)
            o[j] = (_Float16)wx[(l4 * 8 + j) * 32 + nf * 16 + l16];
        dst = (_Float16*)(ws + F_WX2) + (size_t)i * 8;
    }
    *(half8*)dst = o;
}

// ---------------------------------------------------------------------------
__global__ __launch_bounds__(256, 4) void gGH_kernel(
    const float* __restrict__ feat0e, const float* __restrict__ feat1o,
    const char* __restrict__ wsp,
    int lo, int hi, _Float16* __restrict__ GH, _Float16* __restrict__ aux)
{
    const int tid = threadIdx.x, w = tid >> 6, lane = tid & 63;
    const int l4 = lane >> 4, l16 = lane & 15;
    const int n0 = lo + blockIdx.x * 16;
    if (n0 >= hi) return;

    if (blockIdx.y == 0) {
        half8 af[2];
        {
            int n = n0 + l16; if (n >= NN) n = NN - 1;
            const float* sp = feat0e + (size_t)n * 64 + l4 * 8;
            af[0] = pack8(*(const float4*)sp, *(const float4*)(sp + 4));
            af[1] = pack8(*(const float4*)(sp + 32), *(const float4*)(sp + 36));
        }
        const half8* wg = (const half8*)(wsp + F_WSSG);
#pragma unroll 2
        for (int qq = 0; qq < 16; ++qq) {
            const int q = w * 16 + qq;
            f32x4 acc[4];
#pragma unroll
            for (int nf = 0; nf < 4; nf++) acc[nf] = (f32x4){0.f,0.f,0.f,0.f};
#pragma unroll
            for (int kf = 0; kf < 2; kf++)
#pragma unroll
                for (int nf = 0; nf < 4; nf++)
                    acc[nf] = __builtin_amdgcn_mfma_f32_16x16x32_f16(
                        af[kf], wg[(q * 8 + kf * 4 + nf) * 64 + lane], acc[nf], 0, 0, 0);
#pragma unroll
            for (int nf = 0; nf < 4; nf++)
#pragma unroll
                for (int reg = 0; reg < 4; reg++) {
                    int n = n0 + l4 * 4 + reg;
                    if (n < hi && n < NN)
                        GH[(size_t)(n - lo) * 10240 + q * 64 + nf * 16 + l16] =
                            (_Float16)acc[nf][reg];
                }
        }
        if (w == 0) {
            const half8* wsvp = (const half8*)(wsp + F_WSV);
            f32x4 accg[2];
#pragma unroll
            for (int nf = 0; nf < 2; nf++) accg[nf] = (f32x4){0.f,0.f,0.f,0.f};
#pragma unroll
            for (int kf = 0; kf < 2; kf++)
#pragma unroll
                for (int nf = 0; nf < 2; nf++)
                    accg[nf] = __builtin_amdgcn_mfma_f32_16x16x32_f16(
                        af[kf], wsvp[(kf * 2 + nf) * 64 + lane], accg[nf], 0, 0, 0);
#pragma unroll
            for (int nf = 0; nf < 2; nf++)
#pragma unroll
                for (int reg = 0; reg < 4; reg++) {
                    int n = n0 + l4 * 4 + reg;
                    if (n < hi && n < NN)
                        aux[(size_t)n * 512 + nf * 16 + l16] = (_Float16)accg[nf][reg];
                }
        }
    } else {
        const int x = blockIdx.y - 1;
        half8 av;
        {
            int nn = n0 + l16; if (nn >= NN) nn = NN - 1;
#pragma unroll
            for (int j = 0; j < 8; j++)
                av[j] = (_Float16)feat1o[(size_t)nn * 96 + (l4 * 8 + j) * 3 + x];
        }
        const half8* wvs3 = (const half8*)(wsp + F_WVS3);
#pragma unroll 4
        for (int ff = 0; ff < 32; ++ff) {
            const int f = w * 32 + ff;
            f32x4 acc = __builtin_amdgcn_mfma_f32_16x16x32_f16(
                av, wvs3[f * 64 + lane], (f32x4){0.f,0.f,0.f,0.f}, 0, 0, 0);
#pragma unroll
            for (int reg = 0; reg < 4; reg++) {
                int n = n0 + l4 * 4 + reg;
                if (n < hi && n < NN)
                    GH[(size_t)(n - lo) * 10240 + 4096 + x * 2048 + f * 16 + l16] =
                        (_Float16)acc[reg];
            }
        }
        if (w == 0) {
            const half8* wvvp = (const half8*)(wsp + F_WVV);
            const half8* wx2  = (const half8*)(wsp + F_WX2);
#pragma unroll
            for (int nf = 0; nf < 4; ++nf) {
                f32x4 acc = __builtin_amdgcn_mfma_f32_16x16x32_f16(
                    av, wvvp[nf * 64 + lane], (f32x4){0.f,0.f,0.f,0.f}, 0, 0, 0);
#pragma unroll
                for (int reg = 0; reg < 4; reg++) {
                    int n = n0 + l4 * 4 + reg;
                    if (n < hi && n < NN)
                        aux[(size_t)n * 512 + 128 + x * 64 + nf * 16 + l16] =
                            (_Float16)acc[reg];
                }
            }
#pragma unroll
            for (int nf = 0; nf < 2; ++nf) {
                f32x4 acc = __builtin_amdgcn_mfma_f32_16x16x32_f16(
                    av, wx2[nf * 64 + lane], (f32x4){0.f,0.f,0.f,0.f}, 0, 0, 0);
#pragma unroll
                for (int reg = 0; reg < 4; reg++) {
                    int n = n0 + l4 * 4 + reg;
                    if (n < hi && n < NN)
                        aux[(size_t)n * 512 + 32 + x * 32 + nf * 16 + l16] =
                            (_Float16)acc[reg];
                }
            }
        }
    }
}

// ---------------------------------------------------------------------------
__global__ __launch_bounds__(256, 4) void es_kernel(
    const float* __restrict__ edge_attr,
    const float* __restrict__ b1, const float* __restrict__ b2,
    const float* __restrict__ b3,
    const char* __restrict__ wsp,
    const int* __restrict__ eidx, const int* __restrict__ flag,
    int* __restrict__ curS, int* __restrict__ cur,
    int* __restrict__ dstP, int* __restrict__ pdP,
    _Float16* __restrict__ es)
{
    __shared__ half8 wml[1536];
    __shared__ __align__(16) unsigned short xch[4][1024];
    __shared__ int posl[4][16];

    const int tid = threadIdx.x, w = tid >> 6, lane = tid & 63;
    const int l4 = lane >> 4, l16 = lane & 15;
    const int e0 = blockIdx.x * 64 + w * 16;

    if (l4 == 0) {
        int e = e0 + l16;
        int s_, d_; load_sd(eidx, flag, e, s_, d_);
        int posS = atomicAdd(curS + s_, 1);
        int posD = atomicAdd(cur + d_, 1);
        dstP[posS] = d_; pdP[posS] = posD;
        posl[w][l16] = posS;
    }
    {
        const half8* wm = (const half8*)(wsp + F_WMLP);
        for (int f = tid; f < 1536; f += 256) wml[f] = wm[f];
    }
    __syncthreads();

    float bias[3][4];
#pragma unroll
    for (int nf = 0; nf < 4; nf++) {
        bias[0][nf] = b1[nf * 16 + l16];
        bias[1][nf] = b2[nf * 16 + l16];
        bias[2][nf] = b3[nf * 16 + l16];
    }

    half8 af[2];
    {
        const float* ap = edge_attr + (size_t)(e0 + l16) * 64 + l4 * 8;
        af[0] = pack8(*(const float4*)ap, *(const float4*)(ap + 4));
        af[1] = pack8(*(const float4*)(ap + 32), *(const float4*)(ap + 36));
    }

    unsigned short* x = xch[w];
    const int sw16 = (l16 & 7) << 3;

#pragma unroll
    for (int layer = 0; layer < 3; ++layer) {
        f32x4 acc[4];
#pragma unroll
        for (int nf = 0; nf < 4; nf++) acc[nf] = (f32x4){0.f,0.f,0.f,0.f};
#pragma unroll
        for (int kf = 0; kf < 2; kf++)
#pragma unroll
            for (int nf = 0; nf < 4; nf++)
                acc[nf] = __builtin_amdgcn_mfma_f32_16x16x32_f16(
                    af[kf], wml[(layer * 8 + kf * 4 + nf) * 64 + lane],
                    acc[nf], 0, 0, 0);
#pragma unroll
        for (int nf = 0; nf < 4; nf++)
#pragma unroll
            for (int reg = 0; reg < 4; reg++) {
                int row = l4 * 4 + reg;
                int col = nf * 16 + l16;
                float v = acc[nf][reg] + bias[layer][nf];
                if (layer < 2) v = silu_f(v);
                x[row * 64 + (col ^ ((row & 7) << 3))] = h2u((_Float16)v);
            }
        if (layer < 2) {
#pragma unroll
            for (int kf = 0; kf < 2; kf++)
                af[kf] = *(const half8*)&x[l16 * 64 + ((kf * 32 + l4 * 8) ^ sw16)];
        }
    }
#pragma unroll
    for (int i = 0; i < 2; i++) {
        int row16 = i * 8 + (lane >> 3);
        int ps = posl[w][row16];
        int c8 = lane & 7;
        half8 v = *(const half8*)&x[row16 * 64 + ((c8 * 8) ^ ((row16 & 7) << 3))];
        *(half8*)(es + (size_t)ps * 64 + c8 * 8) = v;
    }
}

// ---------------------------------------------------------------------------
__global__ __launch_bounds__(256, 3) void msg01_node_kernel(
    const float* __restrict__ pos,
    const char* __restrict__ wsp,
    const _Float16* __restrict__ GH,
    const _Float16* __restrict__ es,
    int lo, int hi,
    _Float16* __restrict__ msg)
{
    __shared__ __align__(16) unsigned short xch[4][16 * 104];
    __shared__ float relb[4][16][4];
    __shared__ __align__(16) unsigned short auxl[4][320];

    const int tid = threadIdx.x, w = tid >> 6, lane = tid & 63;
    const int l4 = lane >> 4, l16 = lane & 15;

    const int n = lo + blockIdx.x * 4 + w;
    if (n >= hi) return;
    const int deg = ((const int*)(wsp + F_OUTD))[n];
    if (deg == 0) return;
    const int base = ((const int*)(wsp + F_PSP))[n];
    const int* dstP = (const int*)(wsp + F_DSTP);
    const int* pdP  = (const int*)(wsp + F_PDP);
    const int ntile = (deg + 15) >> 4;

    int rowcA = l16 < deg - 1 ? l16 : deg - 1;
    int ddA = dstP[base + rowcA];
    half8 eA0, eA1;
    {
        const _Float16* ep = es + (size_t)(base + rowcA) * 64;
        eA0 = *(const half8*)(ep + l4 * 8);
        eA1 = *(const half8*)(ep + 32 + l4 * 8);
    }

    const float pn0 = pos[n * 3 + 0], pn1 = pos[n * 3 + 1], pn2 = pos[n * 3 + 2];

    const size_t kbase = (size_t)(n - lo) * 10240;
    half8 Gr[8];
    {
        const half8* gn = (const half8*)(GH + kbase);
#pragma unroll
        for (int f = 0; f < 8; f++) Gr[f] = gn[f * 64 + lane];
    }
    half8 Hf[2][6];
    {
        const _Float16* Hg = GH + kbase + 4096;
#pragma unroll
        for (int x = 0; x < 3; x++)
#pragma unroll
            for (int nfc = 0; nfc < 2; nfc++)
#pragma unroll
                for (int kf = 0; kf < 2; kf++)
                    Hf[kf][x * 2 + nfc] = *(const half8*)(
                        Hg + x * 2048 + (nfc * 16 + l16) * 64 + kf * 32 + l4 * 8);
    }
    {
        const _Float16* ag = (const _Float16*)(wsp + F_AUX) + (size_t)n * 512;
        if (lane < 40) ((half8*)auxl[w])[lane] = ((const half8*)ag)[lane];
    }

    unsigned short* x = xch[w];

    for (int t = 0; t < ntile; ++t) {
        const float rel0 = pos[ddA * 3 + 0] - pn0;
        const float rel1 = pos[ddA * 3 + 1] - pn1;
        const float rel2 = pos[ddA * 3 + 2] - pn2;
        if (l4 == 0) {
            relb[w][l16][0] = rel0; relb[w][l16][1] = rel1; relb[w][l16][2] = rel2;
        }

        half8 e0 = eA0, e1 = eA1;
        const int r0 = t * 16;

        if (t + 1 < ntile) {
            int rc = (t + 1) * 16 + l16; if (rc > deg - 1) rc = deg - 1;
            rowcA = rc;
            ddA = dstP[base + rc];
            const _Float16* ep = es + (size_t)(base + rc) * 64;
            eA0 = *(const half8*)(ep + l4 * 8);
            eA1 = *(const half8*)(ep + 32 + l4 * 8);
        }

        // ---- msg0: es@G + VW·rel ----
        {
            f32x4 acc0[4];
#pragma unroll
            for (int nf = 0; nf < 4; nf++) acc0[nf] = (f32x4){0.f,0.f,0.f,0.f};
#pragma unroll
            for (int kf = 0; kf < 2; kf++)
#pragma unroll
                for (int nf = 0; nf < 4; nf++)
                    acc0[nf] = __builtin_amdgcn_mfma_f32_16x16x32_f16(
                        kf == 0 ? e0 : e1, Gr[kf * 4 + nf], acc0[nf], 0, 0, 0);
#pragma unroll
            for (int nf = 0; nf < 4; nf++) {
                float vw0 = (float)u2h(auxl[w][128 + 0 * 64 + nf * 16 + l16]);
                float vw1 = (float)u2h(auxl[w][128 + 1 * 64 + nf * 16 + l16]);
                float vw2 = (float)u2h(auxl[w][128 + 2 * 64 + nf * 16 + l16]);
#pragma unroll
                for (int reg = 0; reg < 4; reg++) {
                    int row = l4 * 4 + reg;
                    float v = acc0[nf][reg]
                            + relb[w][row][0] * vw0
                            + relb[w][row][1] * vw1
                            + relb[w][row][2] * vw2;
                    int col = nf * 16 + l16;
                    x[row * 104 + (col ^ ((row & 7) << 3))] = h2u((_Float16)v);
                }
            }
#pragma unroll
            for (int i = 0; i < 2; i++) {
                int row16 = i * 8 + (lane >> 3);
                if (r0 + row16 < deg) {
                    int rowD = pdP[base + r0 + row16];
                    int c8 = lane & 7;
                    half8 v = *(const half8*)&x[row16 * 104 + ((c8 * 8) ^ ((row16 & 7) << 3))];
                    *(half8*)(msg + (size_t)rowD * 160 + c8 * 8) = v;
                }
            }
        }

        // ---- msg1: es@H + g/CXW epilogue ----
        {
            f32x4 acc1[6];
#pragma unroll
            for (int nf = 0; nf < 6; nf++) acc1[nf] = (f32x4){0.f,0.f,0.f,0.f};
#pragma unroll
            for (int kf = 0; kf < 2; kf++)
#pragma unroll
                for (int nf = 0; nf < 6; nf++)
                    acc1[nf] = __builtin_amdgcn_mfma_f32_16x16x32_f16(
                        kf == 0 ? e0 : e1, Hf[kf][nf], acc1[nf], 0, 0, 0);
#pragma unroll
            for (int nf = 0; nf < 6; nf++) {
                const int xx = nf >> 1;
                const int x1 = (xx + 1) % 3, x2 = (xx + 2) % 3;
                const int c = (nf & 1) * 16 + l16;
                const float gv  = (float)u2h(auxl[w][c]);
                const float cw1 = (float)u2h(auxl[w][32 + x1 * 32 + c]);
                const float cw2 = (float)u2h(auxl[w][32 + x2 * 32 + c]);
#pragma unroll
                for (int reg = 0; reg < 4; reg++) {
                    int row = l4 * 4 + reg;
                    float val = acc1[nf][reg]
                              + gv * relb[w][row][xx]
                              + relb[w][row][x2] * cw1
                              - relb[w][row][x1] * cw2;
                    int col = nf * 16 + l16;
                    x[row * 104 + (col ^ ((row & 3) << 3))] = h2u((_Float16)val);
                }
            }
            const int rowS = lane >> 2;
            if (r0 + rowS < deg) {
                int rowD = pdP[base + r0 + rowS];
                const int swr = (rowS & 3) << 3;
#pragma unroll
                for (int t3 = 0; t3 < 3; t3++) {
                    int co = ((lane & 3) + 4 * t3) * 8;
                    half8 v = *(const half8*)&x[rowS * 104 + (co ^ swr)];
                    *(half8*)(msg + (size_t)rowD * 160 + 64 + co) = v;
                }
            }
        }
    }
}

// ---------------------------------------------------------------------------
__global__ __launch_bounds__(256) void gather_kernel(
    const float* __restrict__ feat0e, const float* __restrict__ feat1o,
    const float* __restrict__ Wg, const float* __restrict__ bg,
    const char* __restrict__ wsp, const _Float16* __restrict__ msg,
    float* __restrict__ out)
{
    __shared__ float Wgl[2048];
    __shared__ float ag[4][64];
    __shared__ float ag1[4][96];
    __shared__ float gate_lds[4][32];
    const int tid = threadIdx.x, w = tid >> 6, lane = tid & 63;
    for (int t = tid; t < 2048; t += 256) Wgl[t] = Wg[t];
    __syncthreads();

    const int n = blockIdx.x * 4 + w;
    const int* rs = (const int*)(wsp + OFF_RS);
    const int i0 = rs[n], i1 = rs[n + 1];

    {
        const int r8 = lane >> 3, c8 = lane & 7;
        float a[8];
#pragma unroll
        for (int j = 0; j < 8; j++) a[j] = 0.f;
        for (int i = i0 + r8; i < i1; i += 8) {
            half8 m = *(const half8*)(msg + (size_t)i * 160 + c8 * 8);
#pragma unroll
            for (int j = 0; j < 8; j++) a[j] += (float)m[j];
        }
#pragma unroll
        for (int s = 8; s < 64; s <<= 1)
#pragma unroll
            for (int j = 0; j < 8; j++) a[j] += __shfl_xor(a[j], s);
        if (r8 == 0)
#pragma unroll
            for (int j = 0; j < 8; j++) ag[w][c8 * 8 + j] = a[j];
    }
    {
        const int r4 = lane >> 4, c12 = lane & 15;
        float a[8];
#pragma unroll
        for (int j = 0; j < 8; j++) a[j] = 0.f;
        if (c12 < 12)
            for (int i = i0 + r4; i < i1; i += 4) {
                half8 m = *(const half8*)(msg + (size_t)i * 160 + 64 + c12 * 8);
#pragma unroll
                for (int j = 0; j < 8; j++) a[j] += (float)m[j];
            }
#pragma unroll
        for (int s = 16; s < 64; s <<= 1)
#pragma unroll
            for (int j = 0; j < 8; j++) a[j] += __shfl_xor(a[j], s);
        if (r4 == 0 && c12 < 12)
#pragma unroll
            for (int j = 0; j < 8; j++) ag1[w][c12 * 8 + j] = a[j];
    }

    const float inv = 1.0f / fmaxf((float)(i1 - i0), 1.0f);
    out[(size_t)n * 160 + lane] = silu_f(ag[w][lane] * inv) + feat0e[(size_t)n * 64 + lane];
    if (lane < 32) {
        float gs = bg[lane];
#pragma unroll
        for (int p = 0; p < 64; ++p) gs = fmaf(ag[w][p] * inv, Wgl[p * 32 + lane], gs);
        gate_lds[w][lane] = silu_f(gs);
    }
#pragma unroll
    for (int t = 0; t < 2; t++) {
        int idx = t * 64 + lane;
        if (idx < 96) {
            int c = idx / 3, xx = idx - 3 * c;
            float v = ag1[w][xx * 32 + c] * inv * gate_lds[w][c] + feat1o[(size_t)n * 96 + idx];
            out[(size_t)n * 160 + 64 + idx] = v;
        }
    }
}

// ---------------------------------------------------------------------------
extern "C" void kernel_launch(void* const* d_in, const int* in_sizes, int n_in,
                              void* d_out, int out_size, void* d_ws, size_t ws_size,
                              hipStream_t stream) {
    const float* feat0e    = (const float*)d_in[0];
    const float* feat1o    = (const float*)d_in[1];
    const float* edge_attr = (const float*)d_in[2];
    const float* pos       = (const float*)d_in[3];
    const int*   eidx      = (const int*)d_in[4];
    const float* W1 = (const float*)d_in[5];
    const float* b1 = (const float*)d_in[6];
    const float* W2 = (const float*)d_in[7];
    const float* b2 = (const float*)d_in[8];
    const float* W3 = (const float*)d_in[9];
    const float* b3 = (const float*)d_in[10];
    const float* wss    = (const float*)d_in[11];
    const float* wvv    = (const float*)d_in[12];
    const float* wsv    = (const float*)d_in[13];
    const float* wvs    = (const float*)d_in[14];
    const float* wcross = (const float*)d_in[15];
    const float* Wg = (const float*)d_in[16];
    const float* bg = (const float*)d_in[17];

    float* out = (float*)d_out;
    char*  ws  = (char*)d_ws;
    int* hist = (int*)(ws + OFF_HIST);
    int* rs   = (int*)(ws + OFF_RS);
    int* cur  = (int*)(ws + OFF_CUR);
    int* flag = (int*)(ws + OFF_FLAG);
    int* outd = (int*)(ws + F_OUTD);
    int* psP  = (int*)(ws + F_PSP);
    int* curS = (int*)(ws + F_CURS);
    int* dstP = (int*)(ws + F_DSTP);
    int* pdP  = (int*)(ws + F_PDP);
    _Float16* aux  = (_Float16*)(ws + F_AUX);
    _Float16* esb  = (_Float16*)(ws + F_ES);
    _Float16* msgF = (_Float16*)(ws + F_MSG);
    _Float16* GH   = (_Float16*)(ws + F_GH);

    // L3-residency-first tier selection: prefer npp=5000 (GH = 102MB < L3).
    int nppF = 0;
    const int cands[6] = {5000, 2500, 1250, 625, 10000, 20000};
    for (int i = 0; i < 6; ++i)
        if (ws_size >= NEED_F(cands[i])) { nppF = cands[i]; break; }
    if (nppF == 0) return;

    detect_idx_kernel<<<1, 1, 0, stream>>>(eidx, flag);
    hipMemsetAsync(ws + OFF_HIST, 0, NN * sizeof(int), stream);
    hipMemsetAsync(ws + F_OUTD, 0, NN * sizeof(int), stream);

    hist2_kernel<<<EE / 256, 256, 0, stream>>>(eidx, flag, hist, outd);
    scan2_kernel<<<1, 1024, 0, stream>>>(hist, outd, rs, cur, psP, curS);
    prep2_kernel<<<(43136 + 255) / 256, 256, 0, stream>>>(
        wss, wvv, wsv, wvs, wcross, W1, W2, W3, ws);

    es_kernel<<<EE / 64, 256, 0, stream>>>(
        edge_attr, b1, b2, b3, (const char*)ws, eidx, flag, curS, cur,
        dstP, pdP, esb);

    const int S = (NN + nppF - 1) / nppF;
    for (int s = 0; s < S; ++s) {
        int lo = s * nppF;
        int hi = lo + nppF; if (hi > NN) hi = NN;
        const int ngroups = (hi - lo + 15) / 16;
        gGH_kernel<<<dim3(ngroups, 4), 256, 0, stream>>>(
            feat0e, feat1o, (const char*)ws, lo, hi, GH, aux);
        msg01_node_kernel<<<(hi - lo + 3) / 4, 256, 0, stream>>>(
            pos, (const char*)ws, GH, esb, lo, hi, msgF);
    }
    gather_kernel<<<NN / 4, 256, 0, stream>>>(
        feat0e, feat1o, Wg, bg, (const char*)ws, msgF, out);
}

// Round 15
// 722.888 us; speedup vs baseline: 1.0220x; 1.0220x over previous
//
#include <hip/hip_runtime.h>

// EquivariantConvLayer — Round 15.
// r13 pipeline (proven 705us) with one change: es_kernel reads the 24KB MLP
// weight-fragment table directly from global (L2-resident, wave-uniform 16B
// reads) instead of staging to LDS. LDS/block 33->8.3KB, no staging barrier,
// launch_bounds(256,6) -> 24 waves/CU (was LDS-capped at 16). r14's npp=5000
// L3 experiment reverted (4-pass overhead exceeded the residency gain).

#define NN 20000
#define EE 640000
#define EPMAX 940032

typedef _Float16 half8 __attribute__((ext_vector_type(8)));
typedef float f32x4 __attribute__((ext_vector_type(4)));

__device__ __forceinline__ float silu_f(float x) { return x / (1.0f + __expf(-x)); }
__device__ __forceinline__ _Float16 u2h(unsigned short u) {
    union { unsigned short u; _Float16 h; } c; c.u = u; return c.h;
}
__device__ __forceinline__ unsigned short h2u(_Float16 h) {
    union { unsigned short u; _Float16 h; } c; c.h = h; return c.u;
}
__device__ __forceinline__ half8 pack8(float4 a, float4 b) {
    half8 h;
    h[0]=(_Float16)a.x; h[1]=(_Float16)a.y; h[2]=(_Float16)a.z; h[3]=(_Float16)a.w;
    h[4]=(_Float16)b.x; h[5]=(_Float16)b.y; h[6]=(_Float16)b.z; h[7]=(_Float16)b.w;
    return h;
}

// ---- workspace layout (bytes) ----
#define OFF_HIST  0ull
#define OFF_RS    81920ull
#define OFF_CUR   163840ull
#define OFF_FLAG  245760ull
#define F_OUTD    262144ull
#define F_PSP     360448ull
#define F_CURS    458752ull
#define F_AUX     557056ull       // NN*512 f16: g[32], CXW[96]@32, VW[192]@128
#define F_DSTP    21037056ull
#define F_PDP     24797184ull
#define F_WMLP    28557312ull
#define F_WSV     28581888ull
#define F_WX2     28585984ull
#define F_WVV     28588032ull
#define F_WSSG    28592128ull
#define F_WVS3    29116416ull
#define F_ES      29247488ull     // EPMAX*128B
#define F_MSG     149571584ull    // EE*320B
#define F_GH      354371584ull    // npp*20480B
#define NEED_F(npp) (F_GH + (unsigned long long)(npp) * 20480ull)

// ---------------------------------------------------------------------------
__global__ void detect_idx_kernel(const int* __restrict__ eidx, int* __restrict__ flag) {
    int odd_nz = 0, even_nz = 0;
    for (int k = 0; k < 64; ++k) {
        if (eidx[2 * k + 1] != 0) odd_nz = 1;
        if (eidx[2 * k] != 0) even_nz = 1;
    }
    *flag = (!odd_nz && even_nz) ? 1 : 0;
}

__device__ __forceinline__ void load_sd(const int* eidx, const int* flag, int e,
                                        int& s_, int& d_) {
    if (*flag) { s_ = (int)((const long long*)eidx)[e]; d_ = (int)((const long long*)eidx)[EE + e]; }
    else       { s_ = eidx[e];                          d_ = eidx[EE + e]; }
}

__global__ __launch_bounds__(256) void hist2_kernel(
    const int* __restrict__ eidx, const int* __restrict__ flag,
    int* __restrict__ hist, int* __restrict__ outd)
{
    const int e = blockIdx.x * 256 + threadIdx.x;
    int s_, d_; load_sd(eidx, flag, e, s_, d_);
    atomicAdd(hist + d_, 1);
    atomicAdd(outd + s_, 1);
}

__global__ __launch_bounds__(1024) void scan2_kernel(
    const int* __restrict__ hist, const int* __restrict__ outd,
    int* __restrict__ rs, int* __restrict__ cur,
    int* __restrict__ psP, int* __restrict__ curS)
{
    __shared__ int part[1024];
    const int t = threadIdx.x;
    const int base = t * 20;
    {
        int loc[20]; int tot = 0;
#pragma unroll
        for (int k = 0; k < 20; ++k) {
            int n = base + k;
            int h = (n < NN) ? hist[n] : 0;
            loc[k] = tot; tot += h;
        }
        part[t] = tot;
        __syncthreads();
        for (int off = 1; off < 1024; off <<= 1) {
            int v = (t >= off) ? part[t - off] : 0;
            __syncthreads();
            part[t] += v;
            __syncthreads();
        }
        int excl = part[t] - tot;
#pragma unroll
        for (int k = 0; k < 20; ++k) {
            int n = base + k;
            if (n < NN) { rs[n] = excl + loc[k]; cur[n] = excl + loc[k]; }
        }
        if (t == 1023) rs[NN] = part[1023];
    }
    __syncthreads();
    {
        int loc[20]; int tot = 0;
#pragma unroll
        for (int k = 0; k < 20; ++k) {
            int n = base + k;
            int p = (n < NN) ? ((outd[n] + 15) & ~15) : 0;
            loc[k] = tot; tot += p;
        }
        part[t] = tot;
        __syncthreads();
        for (int off = 1; off < 1024; off <<= 1) {
            int v = (t >= off) ? part[t - off] : 0;
            __syncthreads();
            part[t] += v;
            __syncthreads();
        }
        int excl = part[t] - tot;
#pragma unroll
        for (int k = 0; k < 20; ++k) {
            int n = base + k;
            if (n < NN) { psP[n] = excl + loc[k]; curS[n] = excl + loc[k]; }
        }
    }
}

// ---------------------------------------------------------------------------
__global__ __launch_bounds__(256) void prep2_kernel(
    const float* __restrict__ wss, const float* __restrict__ wvv,
    const float* __restrict__ wsv, const float* __restrict__ wvs,
    const float* __restrict__ wx,
    const float* __restrict__ W1, const float* __restrict__ W2,
    const float* __restrict__ W3, char* __restrict__ ws)
{
    int id = blockIdx.x * 256 + threadIdx.x;
    if (id >= 43136) return;
    int l = id & 63;
    int l4 = l >> 4, l16 = l & 15;
    half8 o;
    _Float16* dst;
    if (id < 32768) {                        // WSSG
        int i = id;
        int f = i >> 6;
        int q = f >> 3, kfp = (f >> 2) & 1, nfp = f & 3;
#pragma unroll
        for (int j = 0; j < 8; j++) {
            int p = kfp * 32 + l4 * 8 + j;
            int cc = q * 64 + nfp * 16 + l16;
            int jc = cc & 7, lc = (cc >> 3) & 63, fi = cc >> 9;
            int kfc = fi >> 2, nfc = fi & 3;
            int h = kfc * 32 + (lc >> 4) * 8 + jc;
            int oo = nfc * 16 + (lc & 15);
            o[j] = (_Float16)wss[((size_t)p * 64 + h) * 64 + oo];
        }
        dst = (_Float16*)(ws + F_WSSG) + (size_t)i * 8;
    } else if (id < 40960) {                 // WVS3
        int i = id - 32768;
        int f = i >> 6;
        int col = f * 16 + l16;
#pragma unroll
        for (int j = 0; j < 8; j++) {
            int d = l4 * 8 + j;
            o[j] = (_Float16)wvs[((size_t)d * 64 + (col & 63)) * 32 + (col >> 6)];
        }
        dst = (_Float16*)(ws + F_WVS3) + (size_t)i * 8;
    } else if (id < 42496) {                 // WMLP
        int i = id - 40960; int f = i >> 6;
        int layer = f >> 3, kf = (f >> 2) & 1, nf = f & 3;
        const float* W = layer == 0 ? W1 : (layer == 1 ? W2 : W3);
#pragma unroll
        for (int j = 0; j < 8; j++)
            o[j] = (_Float16)W[(kf * 32 + l4 * 8 + j) * 64 + nf * 16 + l16];
        dst = (_Float16*)(ws + F_WMLP) + (size_t)i * 8;
    } else if (id < 42752) {                 // WVV
        int i = id - 42496; int nf = i >> 6;
#pragma unroll
        for (int j = 0; j < 8; j++)
            o[j] = (_Float16)wvv[(l4 * 8 + j) * 64 + nf * 16 + l16];
        dst = (_Float16*)(ws + F_WVV) + (size_t)i * 8;
    } else if (id < 43008) {                 // WSV
        int i = id - 42752; int frag = i >> 6;
        int kf = frag >> 1, nf = frag & 1;
#pragma unroll
        for (int j = 0; j < 8; j++)
            o[j] = (_Float16)wsv[(kf * 32 + l4 * 8 + j) * 32 + nf * 16 + l16];
        dst = (_Float16*)(ws + F_WSV) + (size_t)i * 8;
    } else {                                 // WX2
        int i = id - 43008; int nf = i >> 6;
#pragma unroll
        for (int j = 0; j < 8; j++)
            o[j] = (_Float16)wx[(l4 * 8 + j) * 32 + nf * 16 + l16];
        dst = (_Float16*)(ws + F_WX2) + (size_t)i * 8;
    }
    *(half8*)dst = o;
}

// ---------------------------------------------------------------------------
__global__ __launch_bounds__(256, 4) void gGH_kernel(
    const float* __restrict__ feat0e, const float* __restrict__ feat1o,
    const char* __restrict__ wsp,
    int lo, int hi, _Float16* __restrict__ GH, _Float16* __restrict__ aux)
{
    const int tid = threadIdx.x, w = tid >> 6, lane = tid & 63;
    const int l4 = lane >> 4, l16 = lane & 15;
    const int n0 = lo + blockIdx.x * 16;
    if (n0 >= hi) return;

    if (blockIdx.y == 0) {
        half8 af[2];
        {
            int n = n0 + l16; if (n >= NN) n = NN - 1;
            const float* sp = feat0e + (size_t)n * 64 + l4 * 8;
            af[0] = pack8(*(const float4*)sp, *(const float4*)(sp + 4));
            af[1] = pack8(*(const float4*)(sp + 32), *(const float4*)(sp + 36));
        }
        const half8* wg = (const half8*)(wsp + F_WSSG);
#pragma unroll 2
        for (int qq = 0; qq < 16; ++qq) {
            const int q = w * 16 + qq;
            f32x4 acc[4];
#pragma unroll
            for (int nf = 0; nf < 4; nf++) acc[nf] = (f32x4){0.f,0.f,0.f,0.f};
#pragma unroll
            for (int kf = 0; kf < 2; kf++)
#pragma unroll
                for (int nf = 0; nf < 4; nf++)
                    acc[nf] = __builtin_amdgcn_mfma_f32_16x16x32_f16(
                        af[kf], wg[(q * 8 + kf * 4 + nf) * 64 + lane], acc[nf], 0, 0, 0);
#pragma unroll
            for (int nf = 0; nf < 4; nf++)
#pragma unroll
                for (int reg = 0; reg < 4; reg++) {
                    int n = n0 + l4 * 4 + reg;
                    if (n < hi && n < NN)
                        GH[(size_t)(n - lo) * 10240 + q * 64 + nf * 16 + l16] =
                            (_Float16)acc[nf][reg];
                }
        }
        if (w == 0) {
            const half8* wsvp = (const half8*)(wsp + F_WSV);
            f32x4 accg[2];
#pragma unroll
            for (int nf = 0; nf < 2; nf++) accg[nf] = (f32x4){0.f,0.f,0.f,0.f};
#pragma unroll
            for (int kf = 0; kf < 2; kf++)
#pragma unroll
                for (int nf = 0; nf < 2; nf++)
                    accg[nf] = __builtin_amdgcn_mfma_f32_16x16x32_f16(
                        af[kf], wsvp[(kf * 2 + nf) * 64 + lane], accg[nf], 0, 0, 0);
#pragma unroll
            for (int nf = 0; nf < 2; nf++)
#pragma unroll
                for (int reg = 0; reg < 4; reg++) {
                    int n = n0 + l4 * 4 + reg;
                    if (n < hi && n < NN)
                        aux[(size_t)n * 512 + nf * 16 + l16] = (_Float16)accg[nf][reg];
                }
        }
    } else {
        const int x = blockIdx.y - 1;
        half8 av;
        {
            int nn = n0 + l16; if (nn >= NN) nn = NN - 1;
#pragma unroll
            for (int j = 0; j < 8; j++)
                av[j] = (_Float16)feat1o[(size_t)nn * 96 + (l4 * 8 + j) * 3 + x];
        }
        const half8* wvs3 = (const half8*)(wsp + F_WVS3);
#pragma unroll 4
        for (int ff = 0; ff < 32; ++ff) {
            const int f = w * 32 + ff;
            f32x4 acc = __builtin_amdgcn_mfma_f32_16x16x32_f16(
                av, wvs3[f * 64 + lane], (f32x4){0.f,0.f,0.f,0.f}, 0, 0, 0);
#pragma unroll
            for (int reg = 0; reg < 4; reg++) {
                int n = n0 + l4 * 4 + reg;
                if (n < hi && n < NN)
                    GH[(size_t)(n - lo) * 10240 + 4096 + x * 2048 + f * 16 + l16] =
                        (_Float16)acc[reg];
            }
        }
        if (w == 0) {
            const half8* wvvp = (const half8*)(wsp + F_WVV);
            const half8* wx2  = (const half8*)(wsp + F_WX2);
#pragma unroll
            for (int nf = 0; nf < 4; ++nf) {
                f32x4 acc = __builtin_amdgcn_mfma_f32_16x16x32_f16(
                    av, wvvp[nf * 64 + lane], (f32x4){0.f,0.f,0.f,0.f}, 0, 0, 0);
#pragma unroll
                for (int reg = 0; reg < 4; reg++) {
                    int n = n0 + l4 * 4 + reg;
                    if (n < hi && n < NN)
                        aux[(size_t)n * 512 + 128 + x * 64 + nf * 16 + l16] =
                            (_Float16)acc[reg];
                }
            }
#pragma unroll
            for (int nf = 0; nf < 2; ++nf) {
                f32x4 acc = __builtin_amdgcn_mfma_f32_16x16x32_f16(
                    av, wx2[nf * 64 + lane], (f32x4){0.f,0.f,0.f,0.f}, 0, 0, 0);
#pragma unroll
                for (int reg = 0; reg < 4; reg++) {
                    int n = n0 + l4 * 4 + reg;
                    if (n < hi && n < NN)
                        aux[(size_t)n * 512 + 32 + x * 32 + nf * 16 + l16] =
                            (_Float16)acc[reg];
                }
            }
        }
    }
}

// ---------------------------------------------------------------------------
// es_kernel: weights read directly from global (L2-resident 24KB table);
// no LDS weight stage, no barrier; waves fully independent.
__global__ __launch_bounds__(256, 6) void es_kernel(
    const float* __restrict__ edge_attr,
    const float* __restrict__ b1, const float* __restrict__ b2,
    const float* __restrict__ b3,
    const char* __restrict__ wsp,
    const int* __restrict__ eidx, const int* __restrict__ flag,
    int* __restrict__ curS, int* __restrict__ cur,
    int* __restrict__ dstP, int* __restrict__ pdP,
    _Float16* __restrict__ es)
{
    __shared__ __align__(16) unsigned short xch[4][1024];
    __shared__ int posl[4][16];

    const int tid = threadIdx.x, w = tid >> 6, lane = tid & 63;
    const int l4 = lane >> 4, l16 = lane & 15;
    const int e0 = blockIdx.x * 64 + w * 16;

    if (l4 == 0) {
        int e = e0 + l16;
        int s_, d_; load_sd(eidx, flag, e, s_, d_);
        int posS = atomicAdd(curS + s_, 1);
        int posD = atomicAdd(cur + d_, 1);
        dstP[posS] = d_; pdP[posS] = posD;
        posl[w][l16] = posS;
    }

    const half8* wm = (const half8*)(wsp + F_WMLP);

    float bias[3][4];
#pragma unroll
    for (int nf = 0; nf < 4; nf++) {
        bias[0][nf] = b1[nf * 16 + l16];
        bias[1][nf] = b2[nf * 16 + l16];
        bias[2][nf] = b3[nf * 16 + l16];
    }

    half8 af[2];
    {
        const float* ap = edge_attr + (size_t)(e0 + l16) * 64 + l4 * 8;
        af[0] = pack8(*(const float4*)ap, *(const float4*)(ap + 4));
        af[1] = pack8(*(const float4*)(ap + 32), *(const float4*)(ap + 36));
    }

    unsigned short* x = xch[w];
    const int sw16 = (l16 & 7) << 3;

#pragma unroll
    for (int layer = 0; layer < 3; ++layer) {
        f32x4 acc[4];
#pragma unroll
        for (int nf = 0; nf < 4; nf++) acc[nf] = (f32x4){0.f,0.f,0.f,0.f};
#pragma unroll
        for (int kf = 0; kf < 2; kf++)
#pragma unroll
            for (int nf = 0; nf < 4; nf++)
                acc[nf] = __builtin_amdgcn_mfma_f32_16x16x32_f16(
                    af[kf], wm[(layer * 8 + kf * 4 + nf) * 64 + lane],
                    acc[nf], 0, 0, 0);
#pragma unroll
        for (int nf = 0; nf < 4; nf++)
#pragma unroll
            for (int reg = 0; reg < 4; reg++) {
                int row = l4 * 4 + reg;
                int col = nf * 16 + l16;
                float v = acc[nf][reg] + bias[layer][nf];
                if (layer < 2) v = silu_f(v);
                x[row * 64 + (col ^ ((row & 7) << 3))] = h2u((_Float16)v);
            }
        if (layer < 2) {
#pragma unroll
            for (int kf = 0; kf < 2; kf++)
                af[kf] = *(const half8*)&x[l16 * 64 + ((kf * 32 + l4 * 8) ^ sw16)];
        }
    }
#pragma unroll
    for (int i = 0; i < 2; i++) {
        int row16 = i * 8 + (lane >> 3);
        int ps = posl[w][row16];
        int c8 = lane & 7;
        half8 v = *(const half8*)&x[row16 * 64 + ((c8 * 8) ^ ((row16 & 7) << 3))];
        *(half8*)(es + (size_t)ps * 64 + c8 * 8) = v;
    }
}

// ---------------------------------------------------------------------------
__global__ __launch_bounds__(256, 3) void msg01_node_kernel(
    const float* __restrict__ pos,
    const char* __restrict__ wsp,
    const _Float16* __restrict__ GH,
    const _Float16* __restrict__ es,
    int lo, int hi,
    _Float16* __restrict__ msg)
{
    __shared__ __align__(16) unsigned short xch[4][16 * 104];
    __shared__ float relb[4][16][4];
    __shared__ __align__(16) unsigned short auxl[4][320];

    const int tid = threadIdx.x, w = tid >> 6, lane = tid & 63;
    const int l4 = lane >> 4, l16 = lane & 15;

    const int n = lo + blockIdx.x * 4 + w;
    if (n >= hi) return;
    const int deg = ((const int*)(wsp + F_OUTD))[n];
    if (deg == 0) return;
    const int base = ((const int*)(wsp + F_PSP))[n];
    const int* dstP = (const int*)(wsp + F_DSTP);
    const int* pdP  = (const int*)(wsp + F_PDP);
    const int ntile = (deg + 15) >> 4;

    int rowcA = l16 < deg - 1 ? l16 : deg - 1;
    int ddA = dstP[base + rowcA];
    half8 eA0, eA1;
    {
        const _Float16* ep = es + (size_t)(base + rowcA) * 64;
        eA0 = *(const half8*)(ep + l4 * 8);
        eA1 = *(const half8*)(ep + 32 + l4 * 8);
    }

    const float pn0 = pos[n * 3 + 0], pn1 = pos[n * 3 + 1], pn2 = pos[n * 3 + 2];

    const size_t kbase = (size_t)(n - lo) * 10240;
    half8 Gr[8];
    {
        const half8* gn = (const half8*)(GH + kbase);
#pragma unroll
        for (int f = 0; f < 8; f++) Gr[f] = gn[f * 64 + lane];
    }
    half8 Hf[2][6];
    {
        const _Float16* Hg = GH + kbase + 4096;
#pragma unroll
        for (int x = 0; x < 3; x++)
#pragma unroll
            for (int nfc = 0; nfc < 2; nfc++)
#pragma unroll
                for (int kf = 0; kf < 2; kf++)
                    Hf[kf][x * 2 + nfc] = *(const half8*)(
                        Hg + x * 2048 + (nfc * 16 + l16) * 64 + kf * 32 + l4 * 8);
    }
    {
        const _Float16* ag = (const _Float16*)(wsp + F_AUX) + (size_t)n * 512;
        if (lane < 40) ((half8*)auxl[w])[lane] = ((const half8*)ag)[lane];
    }

    unsigned short* x = xch[w];

    for (int t = 0; t < ntile; ++t) {
        const float rel0 = pos[ddA * 3 + 0] - pn0;
        const float rel1 = pos[ddA * 3 + 1] - pn1;
        const float rel2 = pos[ddA * 3 + 2] - pn2;
        if (l4 == 0) {
            relb[w][l16][0] = rel0; relb[w][l16][1] = rel1; relb[w][l16][2] = rel2;
        }

        half8 e0 = eA0, e1 = eA1;
        const int r0 = t * 16;

        if (t + 1 < ntile) {
            int rc = (t + 1) * 16 + l16; if (rc > deg - 1) rc = deg - 1;
            rowcA = rc;
            ddA = dstP[base + rc];
            const _Float16* ep = es + (size_t)(base + rc) * 64;
            eA0 = *(const half8*)(ep + l4 * 8);
            eA1 = *(const half8*)(ep + 32 + l4 * 8);
        }

        // ---- msg0: es@G + VW·rel ----
        {
            f32x4 acc0[4];
#pragma unroll
            for (int nf = 0; nf < 4; nf++) acc0[nf] = (f32x4){0.f,0.f,0.f,0.f};
#pragma unroll
            for (int kf = 0; kf < 2; kf++)
#pragma unroll
                for (int nf = 0; nf < 4; nf++)
                    acc0[nf] = __builtin_amdgcn_mfma_f32_16x16x32_f16(
                        kf == 0 ? e0 : e1, Gr[kf * 4 + nf], acc0[nf], 0, 0, 0);
#pragma unroll
            for (int nf = 0; nf < 4; nf++) {
                float vw0 = (float)u2h(auxl[w][128 + 0 * 64 + nf * 16 + l16]);
                float vw1 = (float)u2h(auxl[w][128 + 1 * 64 + nf * 16 + l16]);
                float vw2 = (float)u2h(auxl[w][128 + 2 * 64 + nf * 16 + l16]);
#pragma unroll
                for (int reg = 0; reg < 4; reg++) {
                    int row = l4 * 4 + reg;
                    float v = acc0[nf][reg]
                            + relb[w][row][0] * vw0
                            + relb[w][row][1] * vw1
                            + relb[w][row][2] * vw2;
                    int col = nf * 16 + l16;
                    x[row * 104 + (col ^ ((row & 7) << 3))] = h2u((_Float16)v);
                }
            }
#pragma unroll
            for (int i = 0; i < 2; i++) {
                int row16 = i * 8 + (lane >> 3);
                if (r0 + row16 < deg) {
                    int rowD = pdP[base + r0 + row16];
                    int c8 = lane & 7;
                    half8 v = *(const half8*)&x[row16 * 104 + ((c8 * 8) ^ ((row16 & 7) << 3))];
                    *(half8*)(msg + (size_t)rowD * 160 + c8 * 8) = v;
                }
            }
        }

        // ---- msg1: es@H + g/CXW epilogue ----
        {
            f32x4 acc1[6];
#pragma unroll
            for (int nf = 0; nf < 6; nf++) acc1[nf] = (f32x4){0.f,0.f,0.f,0.f};
#pragma unroll
            for (int kf = 0; kf < 2; kf++)
#pragma unroll
                for (int nf = 0; nf < 6; nf++)
                    acc1[nf] = __builtin_amdgcn_mfma_f32_16x16x32_f16(
                        kf == 0 ? e0 : e1, Hf[kf][nf], acc1[nf], 0, 0, 0);
#pragma unroll
            for (int nf = 0; nf < 6; nf++) {
                const int xx = nf >> 1;
                const int x1 = (xx + 1) % 3, x2 = (xx + 2) % 3;
                const int c = (nf & 1) * 16 + l16;
                const float gv  = (float)u2h(auxl[w][c]);
                const float cw1 = (float)u2h(auxl[w][32 + x1 * 32 + c]);
                const float cw2 = (float)u2h(auxl[w][32 + x2 * 32 + c]);
#pragma unroll
                for (int reg = 0; reg < 4; reg++) {
                    int row = l4 * 4 + reg;
                    float val = acc1[nf][reg]
                              + gv * relb[w][row][xx]
                              + relb[w][row][x2] * cw1
                              - relb[w][row][x1] * cw2;
                    int col = nf * 16 + l16;
                    x[row * 104 + (col ^ ((row & 3) << 3))] = h2u((_Float16)val);
                }
            }
            const int rowS = lane >> 2;
            if (r0 + rowS < deg) {
                int rowD = pdP[base + r0 + rowS];
                const int swr = (rowS & 3) << 3;
#pragma unroll
                for (int t3 = 0; t3 < 3; t3++) {
                    int co = ((lane & 3) + 4 * t3) * 8;
                    half8 v = *(const half8*)&x[rowS * 104 + (co ^ swr)];
                    *(half8*)(msg + (size_t)rowD * 160 + 64 + co) = v;
                }
            }
        }
    }
}

// ---------------------------------------------------------------------------
__global__ __launch_bounds__(256) void gather_kernel(
    const float* __restrict__ feat0e, const float* __restrict__ feat1o,
    const float* __restrict__ Wg, const float* __restrict__ bg,
    const char* __restrict__ wsp, const _Float16* __restrict__ msg,
    float* __restrict__ out)
{
    __shared__ float Wgl[2048];
    __shared__ float ag[4][64];
    __shared__ float ag1[4][96];
    __shared__ float gate_lds[4][32];
    const int tid = threadIdx.x, w = tid >> 6, lane = tid & 63;
    for (int t = tid; t < 2048; t += 256) Wgl[t] = Wg[t];
    __syncthreads();

    const int n = blockIdx.x * 4 + w;
    const int* rs = (const int*)(wsp + OFF_RS);
    const int i0 = rs[n], i1 = rs[n + 1];

    {
        const int r8 = lane >> 3, c8 = lane & 7;
        float a[8];
#pragma unroll
        for (int j = 0; j < 8; j++) a[j] = 0.f;
        for (int i = i0 + r8; i < i1; i += 8) {
            half8 m = *(const half8*)(msg + (size_t)i * 160 + c8 * 8);
#pragma unroll
            for (int j = 0; j < 8; j++) a[j] += (float)m[j];
        }
#pragma unroll
        for (int s = 8; s < 64; s <<= 1)
#pragma unroll
            for (int j = 0; j < 8; j++) a[j] += __shfl_xor(a[j], s);
        if (r8 == 0)
#pragma unroll
            for (int j = 0; j < 8; j++) ag[w][c8 * 8 + j] = a[j];
    }
    {
        const int r4 = lane >> 4, c12 = lane & 15;
        float a[8];
#pragma unroll
        for (int j = 0; j < 8; j++) a[j] = 0.f;
        if (c12 < 12)
            for (int i = i0 + r4; i < i1; i += 4) {
                half8 m = *(const half8*)(msg + (size_t)i * 160 + 64 + c12 * 8);
#pragma unroll
                for (int j = 0; j < 8; j++) a[j] += (float)m[j];
            }
#pragma unroll
        for (int s = 16; s < 64; s <<= 1)
#pragma unroll
            for (int j = 0; j < 8; j++) a[j] += __shfl_xor(a[j], s);
        if (r4 == 0 && c12 < 12)
#pragma unroll
            for (int j = 0; j < 8; j++) ag1[w][c12 * 8 + j] = a[j];
    }

    const float inv = 1.0f / fmaxf((float)(i1 - i0), 1.0f);
    out[(size_t)n * 160 + lane] = silu_f(ag[w][lane] * inv) + feat0e[(size_t)n * 64 + lane];
    if (lane < 32) {
        float gs = bg[lane];
#pragma unroll
        for (int p = 0; p < 64; ++p) gs = fmaf(ag[w][p] * inv, Wgl[p * 32 + lane], gs);
        gate_lds[w][lane] = silu_f(gs);
    }
#pragma unroll
    for (int t = 0; t < 2; t++) {
        int idx = t * 64 + lane;
        if (idx < 96) {
            int c = idx / 3, xx = idx - 3 * c;
            float v = ag1[w][xx * 32 + c] * inv * gate_lds[w][c] + feat1o[(size_t)n * 96 + idx];
            out[(size_t)n * 160 + 64 + idx] = v;
        }
    }
}

// ---------------------------------------------------------------------------
extern "C" void kernel_launch(void* const* d_in, const int* in_sizes, int n_in,
                              void* d_out, int out_size, void* d_ws, size_t ws_size,
                              hipStream_t stream) {
    const float* feat0e    = (const float*)d_in[0];
    const float* feat1o    = (const float*)d_in[1];
    const float* edge_attr = (const float*)d_in[2];
    const float* pos       = (const float*)d_in[3];
    const int*   eidx      = (const int*)d_in[4];
    const float* W1 = (const float*)d_in[5];
    const float* b1 = (const float*)d_in[6];
    const float* W2 = (const float*)d_in[7];
    const float* b2 = (const float*)d_in[8];
    const float* W3 = (const float*)d_in[9];
    const float* b3 = (const float*)d_in[10];
    const float* wss    = (const float*)d_in[11];
    const float* wvv    = (const float*)d_in[12];
    const float* wsv    = (const float*)d_in[13];
    const float* wvs    = (const float*)d_in[14];
    const float* wcross = (const float*)d_in[15];
    const float* Wg = (const float*)d_in[16];
    const float* bg = (const float*)d_in[17];

    float* out = (float*)d_out;
    char*  ws  = (char*)d_ws;
    int* hist = (int*)(ws + OFF_HIST);
    int* rs   = (int*)(ws + OFF_RS);
    int* cur  = (int*)(ws + OFF_CUR);
    int* flag = (int*)(ws + OFF_FLAG);
    int* outd = (int*)(ws + F_OUTD);
    int* psP  = (int*)(ws + F_PSP);
    int* curS = (int*)(ws + F_CURS);
    int* dstP = (int*)(ws + F_DSTP);
    int* pdP  = (int*)(ws + F_PDP);
    _Float16* aux  = (_Float16*)(ws + F_AUX);
    _Float16* esb  = (_Float16*)(ws + F_ES);
    _Float16* msgF = (_Float16*)(ws + F_MSG);
    _Float16* GH   = (_Float16*)(ws + F_GH);

    int nppF = 0;
    const int cands[6] = {20000, 10000, 5000, 2500, 1250, 625};
    for (int i = 0; i < 6; ++i)
        if (ws_size >= NEED_F(cands[i])) { nppF = cands[i]; break; }
    if (nppF == 0) return;

    detect_idx_kernel<<<1, 1, 0, stream>>>(eidx, flag);
    hipMemsetAsync(ws + OFF_HIST, 0, NN * sizeof(int), stream);
    hipMemsetAsync(ws + F_OUTD, 0, NN * sizeof(int), stream);

    hist2_kernel<<<EE / 256, 256, 0, stream>>>(eidx, flag, hist, outd);
    scan2_kernel<<<1, 1024, 0, stream>>>(hist, outd, rs, cur, psP, curS);
    prep2_kernel<<<(43136 + 255) / 256, 256, 0, stream>>>(
        wss, wvv, wsv, wvs, wcross, W1, W2, W3, ws);

    es_kernel<<<EE / 64, 256, 0, stream>>>(
        edge_attr, b1, b2, b3, (const char*)ws, eidx, flag, curS, cur,
        dstP, pdP, esb);

    const int S = (NN + nppF - 1) / nppF;
    for (int s = 0; s < S; ++s) {
        int lo = s * nppF;
        int hi = lo + nppF; if (hi > NN) hi = NN;
        const int ngroups = (hi - lo + 15) / 16;
        gGH_kernel<<<dim3(ngroups, 4), 256, 0, stream>>>(
            feat0e, feat1o, (const char*)ws, lo, hi, GH, aux);
        msg01_node_kernel<<<(hi - lo + 3) / 4, 256, 0, stream>>>(
            pos, (const char*)ws, GH, esb, lo, hi, msgF);
    }
    gather_kernel<<<NN / 4, 256, 0, stream>>>(
        feat0e, feat1o, Wg, bg, (const char*)ws, msgF, out);
}

// Round 16
// 703.952 us; speedup vs baseline: 1.0495x; 1.0269x over previous
//
#include <hip/hip_runtime.h>

// EquivariantConvLayer — FINAL (r13 configuration, measured 705us).
// Pipeline: hist/scan sort prep -> prep2 (weight frag permutations) ->
// es_kernel (edge-parallel MFMA MLP, LDS-staged weights, fused scatter) ->
// per-pass {gGH (G=s@wss, Ht=TTV(v,wvs), g/VW/CXW aux), msg01_node (per-node
// wave, G+H in 80 VGPRs, 20 MFMA per 16-edge tile, pipelined, dst-sorted
// linear msg writes)} -> gather (contiguous per-node reduction + epilogue).
// Tuning ledger (measured): msg01 (256,3)=84VGPR/130us is optimal —
// (256,4)/(256,6) spill (+300-630MB scratch); es LDS-staged (256,4)=113us
// optimal — global-weight variant 131us; npp=10000 optimal — npp=5000
// 4-pass amortization loss.

#define NN 20000
#define EE 640000
#define EPMAX 940032

typedef _Float16 half8 __attribute__((ext_vector_type(8)));
typedef float f32x4 __attribute__((ext_vector_type(4)));

__device__ __forceinline__ float silu_f(float x) { return x / (1.0f + __expf(-x)); }
__device__ __forceinline__ _Float16 u2h(unsigned short u) {
    union { unsigned short u; _Float16 h; } c; c.u = u; return c.h;
}
__device__ __forceinline__ unsigned short h2u(_Float16 h) {
    union { unsigned short u; _Float16 h; } c; c.h = h; return c.u;
}
__device__ __forceinline__ half8 pack8(float4 a, float4 b) {
    half8 h;
    h[0]=(_Float16)a.x; h[1]=(_Float16)a.y; h[2]=(_Float16)a.z; h[3]=(_Float16)a.w;
    h[4]=(_Float16)b.x; h[5]=(_Float16)b.y; h[6]=(_Float16)b.z; h[7]=(_Float16)b.w;
    return h;
}

// ---- workspace layout (bytes) ----
#define OFF_HIST  0ull
#define OFF_RS    81920ull
#define OFF_CUR   163840ull
#define OFF_FLAG  245760ull
#define F_OUTD    262144ull
#define F_PSP     360448ull
#define F_CURS    458752ull
#define F_AUX     557056ull       // NN*512 f16: g[32], CXW[96]@32, VW[192]@128
#define F_DSTP    21037056ull
#define F_PDP     24797184ull
#define F_WMLP    28557312ull
#define F_WSV     28581888ull
#define F_WX2     28585984ull
#define F_WVV     28588032ull
#define F_WSSG    28592128ull
#define F_WVS3    29116416ull
#define F_ES      29247488ull     // EPMAX*128B
#define F_MSG     149571584ull    // EE*320B
#define F_GH      354371584ull    // npp*20480B
#define NEED_F(npp) (F_GH + (unsigned long long)(npp) * 20480ull)

// ---------------------------------------------------------------------------
__global__ void detect_idx_kernel(const int* __restrict__ eidx, int* __restrict__ flag) {
    int odd_nz = 0, even_nz = 0;
    for (int k = 0; k < 64; ++k) {
        if (eidx[2 * k + 1] != 0) odd_nz = 1;
        if (eidx[2 * k] != 0) even_nz = 1;
    }
    *flag = (!odd_nz && even_nz) ? 1 : 0;
}

__device__ __forceinline__ void load_sd(const int* eidx, const int* flag, int e,
                                        int& s_, int& d_) {
    if (*flag) { s_ = (int)((const long long*)eidx)[e]; d_ = (int)((const long long*)eidx)[EE + e]; }
    else       { s_ = eidx[e];                          d_ = eidx[EE + e]; }
}

__global__ __launch_bounds__(256) void hist2_kernel(
    const int* __restrict__ eidx, const int* __restrict__ flag,
    int* __restrict__ hist, int* __restrict__ outd)
{
    const int e = blockIdx.x * 256 + threadIdx.x;
    int s_, d_; load_sd(eidx, flag, e, s_, d_);
    atomicAdd(hist + d_, 1);
    atomicAdd(outd + s_, 1);
}

__global__ __launch_bounds__(1024) void scan2_kernel(
    const int* __restrict__ hist, const int* __restrict__ outd,
    int* __restrict__ rs, int* __restrict__ cur,
    int* __restrict__ psP, int* __restrict__ curS)
{
    __shared__ int part[1024];
    const int t = threadIdx.x;
    const int base = t * 20;
    {
        int loc[20]; int tot = 0;
#pragma unroll
        for (int k = 0; k < 20; ++k) {
            int n = base + k;
            int h = (n < NN) ? hist[n] : 0;
            loc[k] = tot; tot += h;
        }
        part[t] = tot;
        __syncthreads();
        for (int off = 1; off < 1024; off <<= 1) {
            int v = (t >= off) ? part[t - off] : 0;
            __syncthreads();
            part[t] += v;
            __syncthreads();
        }
        int excl = part[t] - tot;
#pragma unroll
        for (int k = 0; k < 20; ++k) {
            int n = base + k;
            if (n < NN) { rs[n] = excl + loc[k]; cur[n] = excl + loc[k]; }
        }
        if (t == 1023) rs[NN] = part[1023];
    }
    __syncthreads();
    {
        int loc[20]; int tot = 0;
#pragma unroll
        for (int k = 0; k < 20; ++k) {
            int n = base + k;
            int p = (n < NN) ? ((outd[n] + 15) & ~15) : 0;
            loc[k] = tot; tot += p;
        }
        part[t] = tot;
        __syncthreads();
        for (int off = 1; off < 1024; off <<= 1) {
            int v = (t >= off) ? part[t - off] : 0;
            __syncthreads();
            part[t] += v;
            __syncthreads();
        }
        int excl = part[t] - tot;
#pragma unroll
        for (int k = 0; k < 20; ++k) {
            int n = base + k;
            if (n < NN) { psP[n] = excl + loc[k]; curS[n] = excl + loc[k]; }
        }
    }
}

// ---------------------------------------------------------------------------
__global__ __launch_bounds__(256) void prep2_kernel(
    const float* __restrict__ wss, const float* __restrict__ wvv,
    const float* __restrict__ wsv, const float* __restrict__ wvs,
    const float* __restrict__ wx,
    const float* __restrict__ W1, const float* __restrict__ W2,
    const float* __restrict__ W3, char* __restrict__ ws)
{
    int id = blockIdx.x * 256 + threadIdx.x;
    if (id >= 43136) return;
    int l = id & 63;
    int l4 = l >> 4, l16 = l & 15;
    half8 o;
    _Float16* dst;
    if (id < 32768) {                        // WSSG
        int i = id;
        int f = i >> 6;
        int q = f >> 3, kfp = (f >> 2) & 1, nfp = f & 3;
#pragma unroll
        for (int j = 0; j < 8; j++) {
            int p = kfp * 32 + l4 * 8 + j;
            int cc = q * 64 + nfp * 16 + l16;
            int jc = cc & 7, lc = (cc >> 3) & 63, fi = cc >> 9;
            int kfc = fi >> 2, nfc = fi & 3;
            int h = kfc * 32 + (lc >> 4) * 8 + jc;
            int oo = nfc * 16 + (lc & 15);
            o[j] = (_Float16)wss[((size_t)p * 64 + h) * 64 + oo];
        }
        dst = (_Float16*)(ws + F_WSSG) + (size_t)i * 8;
    } else if (id < 40960) {                 // WVS3
        int i = id - 32768;
        int f = i >> 6;
        int col = f * 16 + l16;
#pragma unroll
        for (int j = 0; j < 8; j++) {
            int d = l4 * 8 + j;
            o[j] = (_Float16)wvs[((size_t)d * 64 + (col & 63)) * 32 + (col >> 6)];
        }
        dst = (_Float16*)(ws + F_WVS3) + (size_t)i * 8;
    } else if (id < 42496) {                 // WMLP
        int i = id - 40960; int f = i >> 6;
        int layer = f >> 3, kf = (f >> 2) & 1, nf = f & 3;
        const float* W = layer == 0 ? W1 : (layer == 1 ? W2 : W3);
#pragma unroll
        for (int j = 0; j < 8; j++)
            o[j] = (_Float16)W[(kf * 32 + l4 * 8 + j) * 64 + nf * 16 + l16];
        dst = (_Float16*)(ws + F_WMLP) + (size_t)i * 8;
    } else if (id < 42752) {                 // WVV
        int i = id - 42496; int nf = i >> 6;
#pragma unroll
        for (int j = 0; j < 8; j++)
            o[j] = (_Float16)wvv[(l4 * 8 + j) * 64 + nf * 16 + l16];
        dst = (_Float16*)(ws + F_WVV) + (size_t)i * 8;
    } else if (id < 43008) {                 // WSV
        int i = id - 42752; int frag = i >> 6;
        int kf = frag >> 1, nf = frag & 1;
#pragma unroll
        for (int j = 0; j < 8; j++)
            o[j] = (_Float16)wsv[(kf * 32 + l4 * 8 + j) * 32 + nf * 16 + l16];
        dst = (_Float16*)(ws + F_WSV) + (size_t)i * 8;
    } else {                                 // WX2
        int i = id - 43008; int nf = i >> 6;
#pragma unroll
        for (int j = 0; j < 8; j++)
            o[j] = (_Float16)wx[(l4 * 8 + j) * 32 + nf * 16 + l16];
        dst = (_Float16*)(ws + F_WX2) + (size_t)i * 8;
    }
    *(half8*)dst = o;
}

// ---------------------------------------------------------------------------
__global__ __launch_bounds__(256, 4) void gGH_kernel(
    const float* __restrict__ feat0e, const float* __restrict__ feat1o,
    const char* __restrict__ wsp,
    int lo, int hi, _Float16* __restrict__ GH, _Float16* __restrict__ aux)
{
    const int tid = threadIdx.x, w = tid >> 6, lane = tid & 63;
    const int l4 = lane >> 4, l16 = lane & 15;
    const int n0 = lo + blockIdx.x * 16;
    if (n0 >= hi) return;

    if (blockIdx.y == 0) {
        half8 af[2];
        {
            int n = n0 + l16; if (n >= NN) n = NN - 1;
            const float* sp = feat0e + (size_t)n * 64 + l4 * 8;
            af[0] = pack8(*(const float4*)sp, *(const float4*)(sp + 4));
            af[1] = pack8(*(const float4*)(sp + 32), *(const float4*)(sp + 36));
        }
        const half8* wg = (const half8*)(wsp + F_WSSG);
#pragma unroll 2
        for (int qq = 0; qq < 16; ++qq) {
            const int q = w * 16 + qq;
            f32x4 acc[4];
#pragma unroll
            for (int nf = 0; nf < 4; nf++) acc[nf] = (f32x4){0.f,0.f,0.f,0.f};
#pragma unroll
            for (int kf = 0; kf < 2; kf++)
#pragma unroll
                for (int nf = 0; nf < 4; nf++)
                    acc[nf] = __builtin_amdgcn_mfma_f32_16x16x32_f16(
                        af[kf], wg[(q * 8 + kf * 4 + nf) * 64 + lane], acc[nf], 0, 0, 0);
#pragma unroll
            for (int nf = 0; nf < 4; nf++)
#pragma unroll
                for (int reg = 0; reg < 4; reg++) {
                    int n = n0 + l4 * 4 + reg;
                    if (n < hi && n < NN)
                        GH[(size_t)(n - lo) * 10240 + q * 64 + nf * 16 + l16] =
                            (_Float16)acc[nf][reg];
                }
        }
        if (w == 0) {
            const half8* wsvp = (const half8*)(wsp + F_WSV);
            f32x4 accg[2];
#pragma unroll
            for (int nf = 0; nf < 2; nf++) accg[nf] = (f32x4){0.f,0.f,0.f,0.f};
#pragma unroll
            for (int kf = 0; kf < 2; kf++)
#pragma unroll
                for (int nf = 0; nf < 2; nf++)
                    accg[nf] = __builtin_amdgcn_mfma_f32_16x16x32_f16(
                        af[kf], wsvp[(kf * 2 + nf) * 64 + lane], accg[nf], 0, 0, 0);
#pragma unroll
            for (int nf = 0; nf < 2; nf++)
#pragma unroll
                for (int reg = 0; reg < 4; reg++) {
                    int n = n0 + l4 * 4 + reg;
                    if (n < hi && n < NN)
                        aux[(size_t)n * 512 + nf * 16 + l16] = (_Float16)accg[nf][reg];
                }
        }
    } else {
        const int x = blockIdx.y - 1;
        half8 av;
        {
            int nn = n0 + l16; if (nn >= NN) nn = NN - 1;
#pragma unroll
            for (int j = 0; j < 8; j++)
                av[j] = (_Float16)feat1o[(size_t)nn * 96 + (l4 * 8 + j) * 3 + x];
        }
        const half8* wvs3 = (const half8*)(wsp + F_WVS3);
#pragma unroll 4
        for (int ff = 0; ff < 32; ++ff) {
            const int f = w * 32 + ff;
            f32x4 acc = __builtin_amdgcn_mfma_f32_16x16x32_f16(
                av, wvs3[f * 64 + lane], (f32x4){0.f,0.f,0.f,0.f}, 0, 0, 0);
#pragma unroll
            for (int reg = 0; reg < 4; reg++) {
                int n = n0 + l4 * 4 + reg;
                if (n < hi && n < NN)
                    GH[(size_t)(n - lo) * 10240 + 4096 + x * 2048 + f * 16 + l16] =
                        (_Float16)acc[reg];
            }
        }
        if (w == 0) {
            const half8* wvvp = (const half8*)(wsp + F_WVV);
            const half8* wx2  = (const half8*)(wsp + F_WX2);
#pragma unroll
            for (int nf = 0; nf < 4; ++nf) {
                f32x4 acc = __builtin_amdgcn_mfma_f32_16x16x32_f16(
                    av, wvvp[nf * 64 + lane], (f32x4){0.f,0.f,0.f,0.f}, 0, 0, 0);
#pragma unroll
                for (int reg = 0; reg < 4; reg++) {
                    int n = n0 + l4 * 4 + reg;
                    if (n < hi && n < NN)
                        aux[(size_t)n * 512 + 128 + x * 64 + nf * 16 + l16] =
                            (_Float16)acc[reg];
                }
            }
#pragma unroll
            for (int nf = 0; nf < 2; ++nf) {
                f32x4 acc = __builtin_amdgcn_mfma_f32_16x16x32_f16(
                    av, wx2[nf * 64 + lane], (f32x4){0.f,0.f,0.f,0.f}, 0, 0, 0);
#pragma unroll
                for (int reg = 0; reg < 4; reg++) {
                    int n = n0 + l4 * 4 + reg;
                    if (n < hi && n < NN)
                        aux[(size_t)n * 512 + 32 + x * 32 + nf * 16 + l16] =
                            (_Float16)acc[reg];
                }
            }
        }
    }
}

// ---------------------------------------------------------------------------
__global__ __launch_bounds__(256, 4) void es_kernel(
    const float* __restrict__ edge_attr,
    const float* __restrict__ b1, const float* __restrict__ b2,
    const float* __restrict__ b3,
    const char* __restrict__ wsp,
    const int* __restrict__ eidx, const int* __restrict__ flag,
    int* __restrict__ curS, int* __restrict__ cur,
    int* __restrict__ dstP, int* __restrict__ pdP,
    _Float16* __restrict__ es)
{
    __shared__ half8 wml[1536];
    __shared__ __align__(16) unsigned short xch[4][1024];
    __shared__ int posl[4][16];

    const int tid = threadIdx.x, w = tid >> 6, lane = tid & 63;
    const int l4 = lane >> 4, l16 = lane & 15;
    const int e0 = blockIdx.x * 64 + w * 16;

    if (l4 == 0) {
        int e = e0 + l16;
        int s_, d_; load_sd(eidx, flag, e, s_, d_);
        int posS = atomicAdd(curS + s_, 1);
        int posD = atomicAdd(cur + d_, 1);
        dstP[posS] = d_; pdP[posS] = posD;
        posl[w][l16] = posS;
    }
    {
        const half8* wm = (const half8*)(wsp + F_WMLP);
        for (int f = tid; f < 1536; f += 256) wml[f] = wm[f];
    }
    __syncthreads();

    float bias[3][4];
#pragma unroll
    for (int nf = 0; nf < 4; nf++) {
        bias[0][nf] = b1[nf * 16 + l16];
        bias[1][nf] = b2[nf * 16 + l16];
        bias[2][nf] = b3[nf * 16 + l16];
    }

    half8 af[2];
    {
        const float* ap = edge_attr + (size_t)(e0 + l16) * 64 + l4 * 8;
        af[0] = pack8(*(const float4*)ap, *(const float4*)(ap + 4));
        af[1] = pack8(*(const float4*)(ap + 32), *(const float4*)(ap + 36));
    }

    unsigned short* x = xch[w];
    const int sw16 = (l16 & 7) << 3;

#pragma unroll
    for (int layer = 0; layer < 3; ++layer) {
        f32x4 acc[4];
#pragma unroll
        for (int nf = 0; nf < 4; nf++) acc[nf] = (f32x4){0.f,0.f,0.f,0.f};
#pragma unroll
        for (int kf = 0; kf < 2; kf++)
#pragma unroll
            for (int nf = 0; nf < 4; nf++)
                acc[nf] = __builtin_amdgcn_mfma_f32_16x16x32_f16(
                    af[kf], wml[(layer * 8 + kf * 4 + nf) * 64 + lane],
                    acc[nf], 0, 0, 0);
#pragma unroll
        for (int nf = 0; nf < 4; nf++)
#pragma unroll
            for (int reg = 0; reg < 4; reg++) {
                int row = l4 * 4 + reg;
                int col = nf * 16 + l16;
                float v = acc[nf][reg] + bias[layer][nf];
                if (layer < 2) v = silu_f(v);
                x[row * 64 + (col ^ ((row & 7) << 3))] = h2u((_Float16)v);
            }
        if (layer < 2) {
#pragma unroll
            for (int kf = 0; kf < 2; kf++)
                af[kf] = *(const half8*)&x[l16 * 64 + ((kf * 32 + l4 * 8) ^ sw16)];
        }
    }
#pragma unroll
    for (int i = 0; i < 2; i++) {
        int row16 = i * 8 + (lane >> 3);
        int ps = posl[w][row16];
        int c8 = lane & 7;
        half8 v = *(const half8*)&x[row16 * 64 + ((c8 * 8) ^ ((row16 & 7) << 3))];
        *(half8*)(es + (size_t)ps * 64 + c8 * 8) = v;
    }
}

// ---------------------------------------------------------------------------
__global__ __launch_bounds__(256, 3) void msg01_node_kernel(
    const float* __restrict__ pos,
    const char* __restrict__ wsp,
    const _Float16* __restrict__ GH,
    const _Float16* __restrict__ es,
    int lo, int hi,
    _Float16* __restrict__ msg)
{
    __shared__ __align__(16) unsigned short xch[4][16 * 104];
    __shared__ float relb[4][16][4];
    __shared__ __align__(16) unsigned short auxl[4][320];

    const int tid = threadIdx.x, w = tid >> 6, lane = tid & 63;
    const int l4 = lane >> 4, l16 = lane & 15;

    const int n = lo + blockIdx.x * 4 + w;
    if (n >= hi) return;
    const int deg = ((const int*)(wsp + F_OUTD))[n];
    if (deg == 0) return;
    const int base = ((const int*)(wsp + F_PSP))[n];
    const int* dstP = (const int*)(wsp + F_DSTP);
    const int* pdP  = (const int*)(wsp + F_PDP);
    const int ntile = (deg + 15) >> 4;

    int rowcA = l16 < deg - 1 ? l16 : deg - 1;
    int ddA = dstP[base + rowcA];
    half8 eA0, eA1;
    {
        const _Float16* ep = es + (size_t)(base + rowcA) * 64;
        eA0 = *(const half8*)(ep + l4 * 8);
        eA1 = *(const half8*)(ep + 32 + l4 * 8);
    }

    const float pn0 = pos[n * 3 + 0], pn1 = pos[n * 3 + 1], pn2 = pos[n * 3 + 2];

    const size_t kbase = (size_t)(n - lo) * 10240;
    half8 Gr[8];
    {
        const half8* gn = (const half8*)(GH + kbase);
#pragma unroll
        for (int f = 0; f < 8; f++) Gr[f] = gn[f * 64 + lane];
    }
    half8 Hf[2][6];
    {
        const _Float16* Hg = GH + kbase + 4096;
#pragma unroll
        for (int x = 0; x < 3; x++)
#pragma unroll
            for (int nfc = 0; nfc < 2; nfc++)
#pragma unroll
                for (int kf = 0; kf < 2; kf++)
                    Hf[kf][x * 2 + nfc] = *(const half8*)(
                        Hg + x * 2048 + (nfc * 16 + l16) * 64 + kf * 32 + l4 * 8);
    }
    {
        const _Float16* ag = (const _Float16*)(wsp + F_AUX) + (size_t)n * 512;
        if (lane < 40) ((half8*)auxl[w])[lane] = ((const half8*)ag)[lane];
    }

    unsigned short* x = xch[w];

    for (int t = 0; t < ntile; ++t) {
        const float rel0 = pos[ddA * 3 + 0] - pn0;
        const float rel1 = pos[ddA * 3 + 1] - pn1;
        const float rel2 = pos[ddA * 3 + 2] - pn2;
        if (l4 == 0) {
            relb[w][l16][0] = rel0; relb[w][l16][1] = rel1; relb[w][l16][2] = rel2;
        }

        half8 e0 = eA0, e1 = eA1;
        const int r0 = t * 16;

        if (t + 1 < ntile) {
            int rc = (t + 1) * 16 + l16; if (rc > deg - 1) rc = deg - 1;
            rowcA = rc;
            ddA = dstP[base + rc];
            const _Float16* ep = es + (size_t)(base + rc) * 64;
            eA0 = *(const half8*)(ep + l4 * 8);
            eA1 = *(const half8*)(ep + 32 + l4 * 8);
        }

        // ---- msg0: es@G + VW·rel ----
        {
            f32x4 acc0[4];
#pragma unroll
            for (int nf = 0; nf < 4; nf++) acc0[nf] = (f32x4){0.f,0.f,0.f,0.f};
#pragma unroll
            for (int kf = 0; kf < 2; kf++)
#pragma unroll
                for (int nf = 0; nf < 4; nf++)
                    acc0[nf] = __builtin_amdgcn_mfma_f32_16x16x32_f16(
                        kf == 0 ? e0 : e1, Gr[kf * 4 + nf], acc0[nf], 0, 0, 0);
#pragma unroll
            for (int nf = 0; nf < 4; nf++) {
                float vw0 = (float)u2h(auxl[w][128 + 0 * 64 + nf * 16 + l16]);
                float vw1 = (float)u2h(auxl[w][128 + 1 * 64 + nf * 16 + l16]);
                float vw2 = (float)u2h(auxl[w][128 + 2 * 64 + nf * 16 + l16]);
#pragma unroll
                for (int reg = 0; reg < 4; reg++) {
                    int row = l4 * 4 + reg;
                    float v = acc0[nf][reg]
                            + relb[w][row][0] * vw0
                            + relb[w][row][1] * vw1
                            + relb[w][row][2] * vw2;
                    int col = nf * 16 + l16;
                    x[row * 104 + (col ^ ((row & 7) << 3))] = h2u((_Float16)v);
                }
            }
#pragma unroll
            for (int i = 0; i < 2; i++) {
                int row16 = i * 8 + (lane >> 3);
                if (r0 + row16 < deg) {
                    int rowD = pdP[base + r0 + row16];
                    int c8 = lane & 7;
                    half8 v = *(const half8*)&x[row16 * 104 + ((c8 * 8) ^ ((row16 & 7) << 3))];
                    *(half8*)(msg + (size_t)rowD * 160 + c8 * 8) = v;
                }
            }
        }

        // ---- msg1: es@H + g/CXW epilogue ----
        {
            f32x4 acc1[6];
#pragma unroll
            for (int nf = 0; nf < 6; nf++) acc1[nf] = (f32x4){0.f,0.f,0.f,0.f};
#pragma unroll
            for (int kf = 0; kf < 2; kf++)
#pragma unroll
                for (int nf = 0; nf < 6; nf++)
                    acc1[nf] = __builtin_amdgcn_mfma_f32_16x16x32_f16(
                        kf == 0 ? e0 : e1, Hf[kf][nf], acc1[nf], 0, 0, 0);
#pragma unroll
            for (int nf = 0; nf < 6; nf++) {
                const int xx = nf >> 1;
                const int x1 = (xx + 1) % 3, x2 = (xx + 2) % 3;
                const int c = (nf & 1) * 16 + l16;
                const float gv  = (float)u2h(auxl[w][c]);
                const float cw1 = (float)u2h(auxl[w][32 + x1 * 32 + c]);
                const float cw2 = (float)u2h(auxl[w][32 + x2 * 32 + c]);
#pragma unroll
                for (int reg = 0; reg < 4; reg++) {
                    int row = l4 * 4 + reg;
                    float val = acc1[nf][reg]
                              + gv * relb[w][row][xx]
                              + relb[w][row][x2] * cw1
                              - relb[w][row][x1] * cw2;
                    int col = nf * 16 + l16;
                    x[row * 104 + (col ^ ((row & 3) << 3))] = h2u((_Float16)val);
                }
            }
            const int rowS = lane >> 2;
            if (r0 + rowS < deg) {
                int rowD = pdP[base + r0 + rowS];
                const int swr = (rowS & 3) << 3;
#pragma unroll
                for (int t3 = 0; t3 < 3; t3++) {
                    int co = ((lane & 3) + 4 * t3) * 8;
                    half8 v = *(const half8*)&x[rowS * 104 + (co ^ swr)];
                    *(half8*)(msg + (size_t)rowD * 160 + 64 + co) = v;
                }
            }
        }
    }
}

// ---------------------------------------------------------------------------
__global__ __launch_bounds__(256) void gather_kernel(
    const float* __restrict__ feat0e, const float* __restrict__ feat1o,
    const float* __restrict__ Wg, const float* __restrict__ bg,
    const char* __restrict__ wsp, const _Float16* __restrict__ msg,
    float* __restrict__ out)
{
    __shared__ float Wgl[2048];
    __shared__ float ag[4][64];
    __shared__ float ag1[4][96];
    __shared__ float gate_lds[4][32];
    const int tid = threadIdx.x, w = tid >> 6, lane = tid & 63;
    for (int t = tid; t < 2048; t += 256) Wgl[t] = Wg[t];
    __syncthreads();

    const int n = blockIdx.x * 4 + w;
    const int* rs = (const int*)(wsp + OFF_RS);
    const int i0 = rs[n], i1 = rs[n + 1];

    {
        const int r8 = lane >> 3, c8 = lane & 7;
        float a[8];
#pragma unroll
        for (int j = 0; j < 8; j++) a[j] = 0.f;
        for (int i = i0 + r8; i < i1; i += 8) {
            half8 m = *(const half8*)(msg + (size_t)i * 160 + c8 * 8);
#pragma unroll
            for (int j = 0; j < 8; j++) a[j] += (float)m[j];
        }
#pragma unroll
        for (int s = 8; s < 64; s <<= 1)
#pragma unroll
            for (int j = 0; j < 8; j++) a[j] += __shfl_xor(a[j], s);
        if (r8 == 0)
#pragma unroll
            for (int j = 0; j < 8; j++) ag[w][c8 * 8 + j] = a[j];
    }
    {
        const int r4 = lane >> 4, c12 = lane & 15;
        float a[8];
#pragma unroll
        for (int j = 0; j < 8; j++) a[j] = 0.f;
        if (c12 < 12)
            for (int i = i0 + r4; i < i1; i += 4) {
                half8 m = *(const half8*)(msg + (size_t)i * 160 + 64 + c12 * 8);
#pragma unroll
                for (int j = 0; j < 8; j++) a[j] += (float)m[j];
            }
#pragma unroll
        for (int s = 16; s < 64; s <<= 1)
#pragma unroll
            for (int j = 0; j < 8; j++) a[j] += __shfl_xor(a[j], s);
        if (r4 == 0 && c12 < 12)
#pragma unroll
            for (int j = 0; j < 8; j++) ag1[w][c12 * 8 + j] = a[j];
    }

    const float inv = 1.0f / fmaxf((float)(i1 - i0), 1.0f);
    out[(size_t)n * 160 + lane] = silu_f(ag[w][lane] * inv) + feat0e[(size_t)n * 64 + lane];
    if (lane < 32) {
        float gs = bg[lane];
#pragma unroll
        for (int p = 0; p < 64; ++p) gs = fmaf(ag[w][p] * inv, Wgl[p * 32 + lane], gs);
        gate_lds[w][lane] = silu_f(gs);
    }
#pragma unroll
    for (int t = 0; t < 2; t++) {
        int idx = t * 64 + lane;
        if (idx < 96) {
            int c = idx / 3, xx = idx - 3 * c;
            float v = ag1[w][xx * 32 + c] * inv * gate_lds[w][c] + feat1o[(size_t)n * 96 + idx];
            out[(size_t)n * 160 + 64 + idx] = v;
        }
    }
}

// ---------------------------------------------------------------------------
extern "C" void kernel_launch(void* const* d_in, const int* in_sizes, int n_in,
                              void* d_out, int out_size, void* d_ws, size_t ws_size,
                              hipStream_t stream) {
    const float* feat0e    = (const float*)d_in[0];
    const float* feat1o    = (const float*)d_in[1];
    const float* edge_attr = (const float*)d_in[2];
    const float* pos       = (const float*)d_in[3];
    const int*   eidx      = (const int*)d_in[4];
    const float* W1 = (const float*)d_in[5];
    const float* b1 = (const float*)d_in[6];
    const float* W2 = (const float*)d_in[7];
    const float* b2 = (const float*)d_in[8];
    const float* W3 = (const float*)d_in[9];
    const float* b3 = (const float*)d_in[10];
    const float* wss    = (const float*)d_in[11];
    const float* wvv    = (const float*)d_in[12];
    const float* wsv    = (const float*)d_in[13];
    const float* wvs    = (const float*)d_in[14];
    const float* wcross = (const float*)d_in[15];
    const float* Wg = (const float*)d_in[16];
    const float* bg = (const float*)d_in[17];

    float* out = (float*)d_out;
    char*  ws  = (char*)d_ws;
    int* hist = (int*)(ws + OFF_HIST);
    int* rs   = (int*)(ws + OFF_RS);
    int* cur  = (int*)(ws + OFF_CUR);
    int* flag = (int*)(ws + OFF_FLAG);
    int* outd = (int*)(ws + F_OUTD);
    int* psP  = (int*)(ws + F_PSP);
    int* curS = (int*)(ws + F_CURS);
    int* dstP = (int*)(ws + F_DSTP);
    int* pdP  = (int*)(ws + F_PDP);
    _Float16* aux  = (_Float16*)(ws + F_AUX);
    _Float16* esb  = (_Float16*)(ws + F_ES);
    _Float16* msgF = (_Float16*)(ws + F_MSG);
    _Float16* GH   = (_Float16*)(ws + F_GH);

    int nppF = 0;
    const int cands[6] = {20000, 10000, 5000, 2500, 1250, 625};
    for (int i = 0; i < 6; ++i)
        if (ws_size >= NEED_F(cands[i])) { nppF = cands[i]; break; }
    if (nppF == 0) return;

    detect_idx_kernel<<<1, 1, 0, stream>>>(eidx, flag);
    hipMemsetAsync(ws + OFF_HIST, 0, NN * sizeof(int), stream);
    hipMemsetAsync(ws + F_OUTD, 0, NN * sizeof(int), stream);

    hist2_kernel<<<EE / 256, 256, 0, stream>>>(eidx, flag, hist, outd);
    scan2_kernel<<<1, 1024, 0, stream>>>(hist, outd, rs, cur, psP, curS);
    prep2_kernel<<<(43136 + 255) / 256, 256, 0, stream>>>(
        wss, wvv, wsv, wvs, wcross, W1, W2, W3, ws);

    es_kernel<<<EE / 64, 256, 0, stream>>>(
        edge_attr, b1, b2, b3, (const char*)ws, eidx, flag, curS, cur,
        dstP, pdP, esb);

    const int S = (NN + nppF - 1) / nppF;
    for (int s = 0; s < S; ++s) {
        int lo = s * nppF;
        int hi = lo + nppF; if (hi > NN) hi = NN;
        const int ngroups = (hi - lo + 15) / 16;
        gGH_kernel<<<dim3(ngroups, 4), 256, 0, stream>>>(
            feat0e, feat1o, (const char*)ws, lo, hi, GH, aux);
        msg01_node_kernel<<<(hi - lo + 3) / 4, 256, 0, stream>>>(
            pos, (const char*)ws, GH, esb, lo, hi, msgF);
    }
    gather_kernel<<<NN / 4, 256, 0, stream>>>(
        feat0e, feat1o, Wg, bg, (const char*)ws, msgF, out);
}